// Round 7
// baseline (40218.140 us; speedup 1.0000x reference)
//
#include <hip/hip_runtime.h>

// LSTM: N=256, L=2048, IN=8, H1=256, H2=128, OUT=1
// 256 WGs x 256 threads; >80KB LDS/WG forces 1 WG/CU -> exactly 32 WGs/XCD.
// Self-assignment from HW_REG_XCC_ID census (verified); groups of 16 WGs are
// PROVABLY same-XCD -> h-exchange through the shared per-XCD L2:
//   producer: plain stores (L1 write-through -> L2)
//   consumer: opportunistic plain load; stale -> global_atomic_add_x2 0 sc0
//             (atomics execute at L2, never L1 -> no stale-spin possible)
// Per-word tags ([tag16|h0|h1]) self-validate; census failure -> all WGs take
// the proven R4 LLC path (agent atomics). No unbounded assumption-gated spin.

typedef __attribute__((ext_vector_type(8))) short short8;
typedef __attribute__((ext_vector_type(4))) float f32x4;
typedef __attribute__((ext_vector_type(4))) unsigned int u32x4;

#define LSEQ 2048

__device__ __forceinline__ unsigned short f2bf(float f) {
  unsigned int u = __float_as_uint(f);
  return (unsigned short)((u + 0x7FFFu + ((u >> 16) & 1u)) >> 16);
}
__device__ __forceinline__ float sigm(float x) {
  float e = __builtin_amdgcn_exp2f(-1.44269504089f * x);
  return __builtin_amdgcn_rcpf(1.0f + e);
}
__device__ __forceinline__ float tanh_(float x) {
  float ax = __builtin_fabsf(x);
  float e = __builtin_amdgcn_exp2f(-2.88539008178f * ax);
  float t = (1.0f - e) * __builtin_amdgcn_rcpf(1.0f + e);
  return __builtin_copysignf(t, x);
}
__device__ __forceinline__ void wg_barrier() {
  __asm__ __volatile__("s_waitcnt lgkmcnt(0)" ::: "memory");
  __builtin_amdgcn_s_barrier();
}
// L2-scope atomic read (bypasses L1 by definition; no sc1 -> stays in-XCD)
__device__ __forceinline__ unsigned long long l2_read(const unsigned long long* a) {
  unsigned long long old, zero = 0ull;
  __asm__ __volatile__(
      "global_atomic_add_x2 %0, %1, %2, off sc0\n\t"
      "s_waitcnt vmcnt(0)"
      : "=&v"(old) : "v"(a), "v"(zero) : "memory");
  return old;
}
__device__ __forceinline__ void plain_store64(unsigned long long* a, unsigned long long v) {
  __asm__ __volatile__("global_store_dwordx2 %0, %1, off" :: "v"(a), "v"(v) : "memory");
}
__device__ __forceinline__ unsigned long long plain_load64(const unsigned long long* a) {
  unsigned long long v;
  __asm__ __volatile__("global_load_dwordx2 %0, %1, off\n\ts_waitcnt vmcnt(0)"
                       : "=&v"(v) : "v"(a));
  return v;
}

// ---------------- prep: weight frag streams + bias + zero xcdid ----------------
// gate frag f = sl*36 + g*9 + kt  (sl 0..15, g 0..3, kt 0..8)
//   lane l, j: col = g*256 + sl*16 + (l&15); k = kt*32 + (l>>4)*8 + j
//   k<256 -> W_hh[col][k]; 256..263 -> W_ih[col][k-256]; else 0 (prev rank-1)
// w1 frag f = nt*8 + kt (nt 0..7): col = nt*16 + (l&15)
__global__ void prep_kernel(const float* __restrict__ W_ih, const float* __restrict__ W_hh,
                            const float* __restrict__ b_ih, const float* __restrict__ b_hh,
                            const float* __restrict__ W1,
                            unsigned short* __restrict__ wstream,
                            unsigned short* __restrict__ w1stream,
                            float* __restrict__ bias,
                            unsigned int* __restrict__ xcdid) {
  int tid = blockIdx.x * 256 + threadIdx.x;
  if (tid < 36864) {                       // 576 gate frags * 64 lanes
    int f = tid >> 6, l = tid & 63;
    int sl = f / 36, rem = f % 36, g = rem / 9, kt = rem % 9;
    int col = g * 256 + sl * 16 + (l & 15);
    int k0 = kt * 32 + (l >> 4) * 8;
    unsigned short* dst = wstream + (size_t)f * 512 + l * 8;
#pragma unroll
    for (int j = 0; j < 8; j++) {
      int k = k0 + j;
      float v;
      if (k < 256)      v = W_hh[col * 256 + k];
      else if (k < 264) v = W_ih[col * 9 + (k - 256)];
      else              v = 0.0f;
      dst[j] = f2bf(v);
    }
  } else if (tid < 36864 + 4096) {         // 64 W1 frags
    int t2 = tid - 36864;
    int f = t2 >> 6, l = t2 & 63;
    int nt = f >> 3, kt = f & 7;
    int col = nt * 16 + (l & 15);
    int k0 = kt * 32 + (l >> 4) * 8;
    unsigned short* dst = w1stream + (size_t)f * 512 + l * 8;
#pragma unroll
    for (int j = 0; j < 8; j++) dst[j] = f2bf(W1[col * 256 + k0 + j]);
  } else if (tid < 36864 + 4096 + 1024) {
    int g = tid - 36864 - 4096;
    bias[g] = b_ih[g] + b_hh[g];
  } else if (tid < 36864 + 4096 + 1024 + 256) {
    xcdid[tid - 41984] = 0u;
  }
}

// ---------------- main: 256 WGs x 256 threads, 1 per CU ----------------
__global__ __launch_bounds__(256, 1) void lstm_main(
    const float* __restrict__ x, const float* __restrict__ W_ih,
    const float* __restrict__ b1, const float* __restrict__ W2, const float* __restrict__ b2,
    const unsigned short* __restrict__ wstream, const unsigned short* __restrict__ w1stream,
    const float* __restrict__ bias,
    unsigned long long* __restrict__ pkt, unsigned int* __restrict__ xcdid,
    float* __restrict__ out0, float* __restrict__ out1, int guard) {
  __shared__ unsigned short A[2][16][296];  // [slot][sample][K]: 0..255 h, 256..263 x, rest 0
  __shared__ float gbuf[4][16][16];         // [gate][sample][local unit]
  __shared__ float part[4][16];             // MLP partials [wave][sample]
  __shared__ unsigned int xl[256];
  __shared__ int hdr[4];
  __shared__ char forcepad[60000];          // forces 1 WG/CU (2*84KB > 160KB LDS)

  const int tid = threadIdx.x;
  const int w = tid >> 6, l = tid & 63, lr = l & 15, lg = l >> 4;
  if (guard == -12345) forcepad[tid] = (char)l;  // never true; keeps pad alive

  // ---- placement census & self-assignment ----
  int my_xcc;
  __asm__ __volatile__("s_getreg_b32 %0, hwreg(HW_REG_XCC_ID)" : "=s"(my_xcc));
  my_xcc &= 7;
  if (tid == 0)
    __hip_atomic_store(&xcdid[blockIdx.x], (unsigned)(my_xcc + 1),
                       __ATOMIC_RELAXED, __HIP_MEMORY_SCOPE_AGENT);
  {
    unsigned v;
    do { v = __hip_atomic_load(&xcdid[tid], __ATOMIC_RELAXED, __HIP_MEMORY_SCOPE_AGENT); }
    while (v == 0u);
    xl[tid] = v - 1;
  }
  __syncthreads();
  if (tid == 0) {
    int cnt[8] = {0, 0, 0, 0, 0, 0, 0, 0};
    int rank = 0, ok = 1;
    for (int b = 0; b < 256; b++) {
      int xb = (int)xl[b];
      if (xb > 7) { ok = 0; xb = 0; }
      if (b < (int)blockIdx.x && xb == my_xcc) rank++;
      cnt[xb]++;
    }
#pragma unroll
    for (int i = 0; i < 8; i++) ok &= (cnt[i] == 32);
    if (ok) { hdr[0] = 1; hdr[1] = my_xcc * 2 + (rank >> 4); hdr[2] = rank & 15; }
    else    { hdr[0] = 0; hdr[1] = (int)(blockIdx.x >> 4);   hdr[2] = (int)(blockIdx.x & 15); }
  }
  __syncthreads();
  const int fast = hdr[0], grp = hdr[1], sl = hdr[2];
  const int n0 = grp * 16, u0 = sl * 16;

  // ---- persistent weights in registers ----
  short8 wg_[9], w1a[8], w1b[8];
  {
    const short8* wp = (const short8*)wstream;
    const short8* w1p = (const short8*)w1stream;
#pragma unroll
    for (int kt = 0; kt < 9; kt++) wg_[kt] = wp[(size_t)(sl * 36 + w * 9 + kt) * 64 + l];
#pragma unroll
    for (int kt = 0; kt < 8; kt++) {
      w1a[kt] = w1p[(size_t)((2 * w) * 8 + kt) * 64 + l];
      w1b[kt] = w1p[(size_t)((2 * w + 1) * 8 + kt) * 64 + l];
    }
  }
  const float bv = bias[w * 256 + u0 + lr];
  const float b1v0 = b1[(2 * w) * 16 + lr], b1v1 = b1[(2 * w + 1) * 16 + lr];
  const float w2v0 = W2[(2 * w) * 16 + lr], w2v1 = W2[(2 * w + 1) * 16 + lr];
  const float b2v = b2[0];

  // cell mapping: thread -> (sample cs, local unit cu)
  const int cs = tid >> 4, cu = tid & 15;
  float wpv[4];
#pragma unroll
  for (int g = 0; g < 4; g++) wpv[g] = W_ih[(g * 256 + u0 + cu) * 9 + 8];
  float c_reg = 0.0f;

  // zero A (both slots, incl. pad cols)
  for (int i = tid; i < 2 * 16 * 296; i += 256) ((unsigned short*)A)[i] = 0;

  // self-zero my packet region (4 slots x 128 words), mode-appropriate stores
  {
    unsigned long long* mybase0 = pkt + (((size_t)0 * 16 + grp) * 16 + sl) * 128;
    for (int z = tid; z < 512; z += 256) {
      int slot = z >> 7, word = z & 127;
      unsigned long long* a = mybase0 + (size_t)slot * 16 * 16 * 128 + word;
      if (fast) plain_store64(a, 0ull);
      else __hip_atomic_store(a, 0ull, __ATOMIC_RELAXED, __HIP_MEMORY_SCOPE_AGENT);
    }
  }
  __asm__ __volatile__("s_waitcnt vmcnt(0)" ::: "memory");
  __syncthreads();   // zeroing durable before any publish

  // x prefetch for k=0 (threads 240..255: sample tid&15)
  f32x4 xa = {0.f, 0.f, 0.f, 0.f}, xb = {0.f, 0.f, 0.f, 0.f};
  if (tid >= 240) {
    const float* xp = x + (size_t)(n0 + (tid & 15)) * LSEQ * 8;
    xa = *(const f32x4*)xp;
    xb = *(const f32x4*)(xp + 4);
  }

  for (int k = 0; k <= LSEQ; k++) {
    const int slot = k & 1;

    // ---- P1: receive h_{k-1} (tagged words) / stage x_k ----
    {
      const int p = tid >> 4, s = tid & 15;
      if (p == 15) {
        if (k < LSEQ) {
          unsigned long long w0 = (unsigned long long)f2bf(xa.x)
                                | ((unsigned long long)f2bf(xa.y) << 16)
                                | ((unsigned long long)f2bf(xa.z) << 32)
                                | ((unsigned long long)f2bf(xa.w) << 48);
          unsigned long long w1 = (unsigned long long)f2bf(xb.x)
                                | ((unsigned long long)f2bf(xb.y) << 16)
                                | ((unsigned long long)f2bf(xb.z) << 32)
                                | ((unsigned long long)f2bf(xb.w) << 48);
          *(unsigned long long*)&A[slot][s][256] = w0;
          *(unsigned long long*)&A[slot][s][260] = w1;
          if (k + 1 < LSEQ) {
            const float* xp = x + ((size_t)(n0 + s) * LSEQ + (k + 1)) * 8;
            xa = *(const f32x4*)xp;
            xb = *(const f32x4*)(xp + 4);
          }
        }
      } else if (k > 0) {
        const int psl = p + (p >= sl ? 1 : 0);
        const unsigned long long* base =
            pkt + ((((size_t)(k & 3) * 16 + grp) * 16 + psl) * 128 + s * 8);
        unsigned long long vw[8];
        if (fast) {
#pragma unroll
          for (int j = 0; j < 8; j++) vw[j] = plain_load64(&base[j]);
#pragma unroll
          for (int j = 0; j < 8; j++)
            while ((int)(vw[j] & 0xFFFFu) != k) vw[j] = l2_read(&base[j]);
        } else {
#pragma unroll
          for (int j = 0; j < 8; j++)
            vw[j] = __hip_atomic_load(&base[j], __ATOMIC_RELAXED, __HIP_MEMORY_SCOPE_AGENT);
#pragma unroll
          for (int j = 0; j < 8; j++)
            while ((int)(vw[j] & 0xFFFFu) != k)
              vw[j] = __hip_atomic_load(&base[j], __ATOMIC_RELAXED, __HIP_MEMORY_SCOPE_AGENT);
        }
        u32x4 d0, d1;
#pragma unroll
        for (int j = 0; j < 4; j++) d0[j] = (unsigned int)(vw[j] >> 16);
#pragma unroll
        for (int j = 0; j < 4; j++) d1[j] = (unsigned int)(vw[4 + j] >> 16);
        u32x4* dst = (u32x4*)&A[slot][s][psl * 16];
        dst[0] = d0;
        dst[1] = d1;
      }
    }
    wg_barrier();   // B1: A[slot] complete

    // ---- P2: gate GEMM (wave = gate) + redundant MLP for out_{k-1} ----
    short8 afr[9];
#pragma unroll
    for (int kt = 0; kt < 9; kt++)
      afr[kt] = *(const short8*)&A[slot][lr][kt * 32 + lg * 8];
    if (k < LSEQ) {
      f32x4 acc = {bv, bv, bv, bv};
#pragma unroll
      for (int kt = 0; kt < 9; kt++)
        acc = __builtin_amdgcn_mfma_f32_16x16x32_bf16(afr[kt], wg_[kt], acc, 0, 0, 0);
#pragma unroll
      for (int r = 0; r < 4; r++) gbuf[w][lg * 4 + r][lr] = acc[r];
    }
    if (k > 0) {
      f32x4 m0 = {b1v0, b1v0, b1v0, b1v0};
      f32x4 m1 = {b1v1, b1v1, b1v1, b1v1};
#pragma unroll
      for (int kt = 0; kt < 8; kt++) {
        m0 = __builtin_amdgcn_mfma_f32_16x16x32_bf16(afr[kt], w1a[kt], m0, 0, 0, 0);
        m1 = __builtin_amdgcn_mfma_f32_16x16x32_bf16(afr[kt], w1b[kt], m1, 0, 0, 0);
      }
      float p[4];
#pragma unroll
      for (int r = 0; r < 4; r++) {
        float v0 = m0[r] > 0.f ? m0[r] : 0.f;
        float v1 = m1[r] > 0.f ? m1[r] : 0.f;
        p[r] = v0 * w2v0 + v1 * w2v1;
        p[r] += __shfl_xor(p[r], 1, 64);
        p[r] += __shfl_xor(p[r], 2, 64);
        p[r] += __shfl_xor(p[r], 4, 64);
        p[r] += __shfl_xor(p[r], 8, 64);
      }
      if (lr == 0) {
#pragma unroll
        for (int r = 0; r < 4; r++) part[w][lg * 4 + r] = p[r];
      }
    }
    wg_barrier();   // B2: gbuf + part ready

    // ---- P3: out reduce + cell update + publish (all 256 threads) ----
    {
      float o = 0.f;
      if (k > 0) {
        o = b2v + part[0][cs] + part[1][cs] + part[2][cs] + part[3][cs];
        if (cu == 0 && sl == 0)
          __builtin_nontemporal_store(o, out0 + (size_t)(n0 + cs) * LSEQ + (k - 1));
      }
      if (k < LSEQ) {
        float gi = gbuf[0][cs][cu] + wpv[0] * o;
        float gf = gbuf[1][cs][cu] + wpv[1] * o;
        float gg = gbuf[2][cs][cu] + wpv[2] * o;
        float go = gbuf[3][cs][cu] + wpv[3] * o;
        float c = sigm(gf) * c_reg + sigm(gi) * tanh_(gg);
        c_reg = c;
        float h = sigm(go) * tanh_(c);
        unsigned int hb = f2bf(h);
        unsigned int ho = (unsigned int)__shfl_xor((int)hb, 1, 64);
        if ((cu & 1) == 0) {   // publish word [tag=k+1 | h(cu) | h(cu+1)]
          unsigned long long wv = (unsigned long long)(unsigned)(k + 1)
                                | ((unsigned long long)hb << 16)
                                | ((unsigned long long)ho << 32);
          unsigned long long* dst =
              pkt + ((((size_t)((k + 1) & 3) * 16 + grp) * 16 + sl) * 128 + cs * 8 + (cu >> 1));
          if (fast) plain_store64(dst, wv);
          else __hip_atomic_store(dst, wv, __ATOMIC_RELAXED, __HIP_MEMORY_SCOPE_AGENT);
        }
        A[slot ^ 1][cs][u0 + cu] = (unsigned short)hb;   // own-slice short circuit
        __builtin_nontemporal_store(
            c, out1 + ((size_t)(n0 + cs) * LSEQ + k) * 256 + u0 + cu);
      }
    }
    // no barrier: P3 LDS reads precede own next-B1; writers of gbuf/part
    // only write after B1(k+1)/B2(k+1); A[slot^1] writer regions disjoint.
  }

  // push dirty packet lines out of this XCD's L2 (replay safety)
  __builtin_amdgcn_fence(__ATOMIC_RELEASE, "agent");
}

extern "C" void kernel_launch(void* const* d_in, const int* in_sizes, int n_in,
                              void* d_out, int out_size, void* d_ws, size_t ws_size,
                              hipStream_t stream) {
  const float* x    = (const float*)d_in[0];
  const float* W_ih = (const float*)d_in[1];
  const float* W_hh = (const float*)d_in[2];
  const float* b_ih = (const float*)d_in[3];
  const float* b_hh = (const float*)d_in[4];
  const float* W1   = (const float*)d_in[5];
  const float* b1   = (const float*)d_in[6];
  const float* W2   = (const float*)d_in[7];
  const float* b2   = (const float*)d_in[8];

  unsigned short*     wstream  = (unsigned short*)d_ws;                      // 589,824 B
  unsigned short*     w1stream = (unsigned short*)((char*)d_ws + 589824);    // 65,536 B
  float*              bias     = (float*)((char*)d_ws + 655360);             // 4,096 B
  unsigned int*       xcdid    = (unsigned int*)((char*)d_ws + 659456);      // 1,024 B
  unsigned long long* pkt      = (unsigned long long*)((char*)d_ws + 660480);// 1,048,576 B

  float* out0 = (float*)d_out;            // [256,2048,1]
  float* out1 = out0 + 256 * LSEQ;        // [256,2048,256]

  prep_kernel<<<165, 256, 0, stream>>>(W_ih, W_hh, b_ih, b_hh, W1,
                                       wstream, w1stream, bias, xcdid);
  lstm_main<<<256, 256, 0, stream>>>(x, W_ih, b1, W2, b2, wstream, w1stream, bias,
                                     pkt, xcdid, out0, out1, 0);
}

// Round 8
// 19333.038 us; speedup vs baseline: 2.0803x; 2.0803x over previous
//
#include <hip/hip_runtime.h>

// LSTM: N=256, L=2048, IN=8, H1=256, H2=128, OUT=1
// 256 WGs x 256 threads. Census via HW_REG_XCC_ID -> groups of 16 WGs that are
// PROVABLY on one XCD (rank construction); h-exchange through the shared L2:
//   producer: dual publish = plain sc0 store (XCD L2) + agent atomic store (LLC)
//   consumer: batched sc0 loads (alias-safe "=&v"); stale -> buffer_inv (L1
//             invalidate, non-dirtying) + sc0 reload; bounded budget ->
//             fallback to LLC buffer (always visible) + permanent trip.
// Per-word tags ([h1|h0|tag16]) self-validate. No RMWs, no fences in-loop,
// no unbounded assumption-gated spins. Census failure -> all WGs slow path.

typedef __attribute__((ext_vector_type(8))) short short8;
typedef __attribute__((ext_vector_type(4))) float f32x4;
typedef __attribute__((ext_vector_type(4))) unsigned int u32x4;

#define LSEQ 2048

__device__ __forceinline__ unsigned short f2bf(float f) {
  unsigned int u = __float_as_uint(f);
  return (unsigned short)((u + 0x7FFFu + ((u >> 16) & 1u)) >> 16);
}
__device__ __forceinline__ float sigm(float x) {
  float e = __builtin_amdgcn_exp2f(-1.44269504089f * x);
  return __builtin_amdgcn_rcpf(1.0f + e);
}
__device__ __forceinline__ float tanh_(float x) {
  float ax = __builtin_fabsf(x);
  float e = __builtin_amdgcn_exp2f(-2.88539008178f * ax);
  float t = (1.0f - e) * __builtin_amdgcn_rcpf(1.0f + e);
  return __builtin_copysignf(t, x);
}
__device__ __forceinline__ void wg_barrier() {
  __asm__ __volatile__("s_waitcnt lgkmcnt(0)" ::: "memory");
  __builtin_amdgcn_s_barrier();
}

// ---------------- prep: weight frag streams + bias + zero pkt/xcdid ----------------
__global__ void prep_kernel(const float* __restrict__ W_ih, const float* __restrict__ W_hh,
                            const float* __restrict__ b_ih, const float* __restrict__ b_hh,
                            const float* __restrict__ W1,
                            unsigned short* __restrict__ wstream,
                            unsigned short* __restrict__ w1stream,
                            float* __restrict__ bias,
                            unsigned long long* __restrict__ pkts,   // both buffers, 2MB
                            unsigned int* __restrict__ xcdid) {
  int tid = blockIdx.x * 256 + threadIdx.x;
  if (tid < 36864) {                       // 576 gate frags * 64 lanes
    int f = tid >> 6, l = tid & 63;
    int sl = f / 36, rem = f % 36, g = rem / 9, kt = rem % 9;
    int col = g * 256 + sl * 16 + (l & 15);
    int k0 = kt * 32 + (l >> 4) * 8;
    unsigned short* dst = wstream + (size_t)f * 512 + l * 8;
#pragma unroll
    for (int j = 0; j < 8; j++) {
      int k = k0 + j;
      float v;
      if (k < 256)      v = W_hh[col * 256 + k];
      else if (k < 264) v = W_ih[col * 9 + (k - 256)];
      else              v = 0.0f;                      // prev handled rank-1
      dst[j] = f2bf(v);
    }
  } else if (tid < 36864 + 4096) {         // 64 W1 frags
    int t2 = tid - 36864;
    int f = t2 >> 6, l = t2 & 63;
    int nt = f >> 3, kt = f & 7;
    int col = nt * 16 + (l & 15);
    int k0 = kt * 32 + (l >> 4) * 8;
    unsigned short* dst = w1stream + (size_t)f * 512 + l * 8;
#pragma unroll
    for (int j = 0; j < 8; j++) dst[j] = f2bf(W1[col * 256 + k0 + j]);
  } else if (tid < 36864 + 4096 + 1024) {
    int g = tid - 36864 - 4096;
    bias[g] = b_ih[g] + b_hh[g];
  } else if (tid < 36864 + 4096 + 1024 + 256) {
    xcdid[tid - 41984] = 0u;
  } else if (tid < 36864 + 4096 + 1024 + 256 + 262144) {
    pkts[tid - 42240] = 0ull;              // tag=0 never matches k>=1
  }
}

// ---------------- main: 256 WGs x 256 threads ----------------
__global__ __launch_bounds__(256, 1) void lstm_main(
    const float* __restrict__ x, const float* __restrict__ W_ih,
    const float* __restrict__ b1, const float* __restrict__ W2, const float* __restrict__ b2,
    const unsigned short* __restrict__ wstream, const unsigned short* __restrict__ w1stream,
    const float* __restrict__ bias,
    unsigned long long* __restrict__ pktF, unsigned long long* __restrict__ pktS,
    unsigned int* __restrict__ xcdid,
    float* __restrict__ out0, float* __restrict__ out1) {
  __shared__ unsigned short A[2][16][296];  // [slot][sample][K]: 0..255 h, 256..263 x, rest 0
  __shared__ float gbuf[4][16][16];         // [gate][sample][local unit]
  __shared__ float part[4][16];             // MLP partials [wave][sample]
  __shared__ unsigned int xl[256];
  __shared__ int hdr[4];

  const int tid = threadIdx.x;
  const int w = tid >> 6, l = tid & 63, lr = l & 15, lg = l >> 4;

  // ---- placement census & self-assignment (proven in R7) ----
  int my_xcc;
  __asm__ __volatile__("s_getreg_b32 %0, hwreg(HW_REG_XCC_ID)" : "=s"(my_xcc));
  my_xcc &= 7;
  if (tid == 0)
    __hip_atomic_store(&xcdid[blockIdx.x], (unsigned)(my_xcc + 1),
                       __ATOMIC_RELAXED, __HIP_MEMORY_SCOPE_AGENT);
  {
    unsigned v;
    do { v = __hip_atomic_load(&xcdid[tid], __ATOMIC_RELAXED, __HIP_MEMORY_SCOPE_AGENT); }
    while (v == 0u);
    xl[tid] = v - 1;
  }
  __syncthreads();
  if (tid == 0) {
    int cnt[8] = {0, 0, 0, 0, 0, 0, 0, 0};
    int rank = 0, ok = 1;
    for (int b = 0; b < 256; b++) {
      int xb = (int)xl[b];
      if (xb > 7) { ok = 0; xb = 0; }
      if (b < (int)blockIdx.x && xb == my_xcc) rank++;
      cnt[xb]++;
    }
#pragma unroll
    for (int i = 0; i < 8; i++) ok &= (cnt[i] == 32);
    if (ok) { hdr[0] = 1; hdr[1] = my_xcc * 2 + (rank >> 4); hdr[2] = rank & 15; }
    else    { hdr[0] = 0; hdr[1] = (int)(blockIdx.x >> 4);   hdr[2] = (int)(blockIdx.x & 15); }
  }
  __syncthreads();
  const int fast0 = hdr[0], grp = hdr[1], sl = hdr[2];
  const int n0 = grp * 16, u0 = sl * 16;

  // ---- persistent weights in registers ----
  short8 wg_[9], w1a[8], w1b[8];
  {
    const short8* wp = (const short8*)wstream;
    const short8* w1p = (const short8*)w1stream;
#pragma unroll
    for (int kt = 0; kt < 9; kt++) wg_[kt] = wp[(size_t)(sl * 36 + w * 9 + kt) * 64 + l];
#pragma unroll
    for (int kt = 0; kt < 8; kt++) {
      w1a[kt] = w1p[(size_t)((2 * w) * 8 + kt) * 64 + l];
      w1b[kt] = w1p[(size_t)((2 * w + 1) * 8 + kt) * 64 + l];
    }
  }
  const float bv = bias[w * 256 + u0 + lr];
  const float b1v0 = b1[(2 * w) * 16 + lr], b1v1 = b1[(2 * w + 1) * 16 + lr];
  const float w2v0 = W2[(2 * w) * 16 + lr], w2v1 = W2[(2 * w + 1) * 16 + lr];
  const float b2v = b2[0];

  const int cs = tid >> 4, cu = tid & 15;   // cell mapping
  float wpv[4];
#pragma unroll
  for (int g = 0; g < 4; g++) wpv[g] = W_ih[(g * 256 + u0 + cu) * 9 + 8];
  float c_reg = 0.0f;

  for (int i = tid; i < 2 * 16 * 296; i += 256) ((unsigned short*)A)[i] = 0;

  // x prefetch for k=0 (threads 240..255: sample tid&15)
  f32x4 xa = {0.f, 0.f, 0.f, 0.f}, xb = {0.f, 0.f, 0.f, 0.f};
  if (tid >= 240) {
    const float* xp = x + (size_t)(n0 + (tid & 15)) * LSEQ * 8;
    xa = *(const f32x4*)xp;
    xb = *(const f32x4*)(xp + 4);
  }

  bool fastOK = (fast0 != 0);   // wave-uniform adaptive state
  __syncthreads();

  for (int k = 0; k <= LSEQ; k++) {
    const int slot = k & 1;

    // ---- P1: receive h_{k-1} (tagged words) / stage x_k ----
    {
      const int p = tid >> 4, s = tid & 15;
      bool good = true;
      if (p == 15) {
        if (k < LSEQ) {
          unsigned long long w0 = (unsigned long long)f2bf(xa.x)
                                | ((unsigned long long)f2bf(xa.y) << 16)
                                | ((unsigned long long)f2bf(xa.z) << 32)
                                | ((unsigned long long)f2bf(xa.w) << 48);
          unsigned long long w1 = (unsigned long long)f2bf(xb.x)
                                | ((unsigned long long)f2bf(xb.y) << 16)
                                | ((unsigned long long)f2bf(xb.z) << 32)
                                | ((unsigned long long)f2bf(xb.w) << 48);
          *(unsigned long long*)&A[slot][s][256] = w0;
          *(unsigned long long*)&A[slot][s][260] = w1;
          if (k + 1 < LSEQ) {
            const float* xp = x + ((size_t)(n0 + s) * LSEQ + (k + 1)) * 8;
            xa = *(const f32x4*)xp;
            xb = *(const f32x4*)(xp + 4);
          }
        }
      } else if (k > 0) {
        const int psl = p + (p >= sl ? 1 : 0);
        const size_t pb = (((size_t)(k & 3) * 16 + grp) * 16 + psl) * 128 + s * 8;
        const unsigned long long* bf = pktF + pb;
        const unsigned long long* bs = pktS + pb;
        unsigned long long vw[8];
        bool all = false;
        if (fastOK) {
          __asm__ __volatile__(
              "global_load_dwordx2 %0, %8, off sc0\n\t"
              "global_load_dwordx2 %1, %8, off offset:8 sc0\n\t"
              "global_load_dwordx2 %2, %8, off offset:16 sc0\n\t"
              "global_load_dwordx2 %3, %8, off offset:24 sc0\n\t"
              "global_load_dwordx2 %4, %8, off offset:32 sc0\n\t"
              "global_load_dwordx2 %5, %8, off offset:40 sc0\n\t"
              "global_load_dwordx2 %6, %8, off offset:48 sc0\n\t"
              "global_load_dwordx2 %7, %8, off offset:56 sc0\n\t"
              "s_waitcnt vmcnt(0)"
              : "=&v"(vw[0]), "=&v"(vw[1]), "=&v"(vw[2]), "=&v"(vw[3]),
                "=&v"(vw[4]), "=&v"(vw[5]), "=&v"(vw[6]), "=&v"(vw[7])
              : "v"(bf) : "memory");
          const int budget = (k == 1) ? 16384 : 64;
          int tries = 0;
          for (;;) {
            all = true;
#pragma unroll
            for (int j = 0; j < 8; j++)
              all = all && ((int)(vw[j] & 0xFFFFu) == k);
            if (all || ++tries > budget) break;
            __asm__ __volatile__("buffer_inv" ::: "memory");  // L1 inv, non-dirtying
#pragma unroll
            for (int j = 0; j < 8; j++)
              if ((int)(vw[j] & 0xFFFFu) != k)
                __asm__ __volatile__(
                    "global_load_dwordx2 %0, %1, off sc0\n\ts_waitcnt vmcnt(0)"
                    : "=&v"(vw[j]) : "v"(&bf[j]) : "memory");
          }
          good = all && (k == 1 || tries <= 16);
        }
        if (!all) {   // guaranteed-visible LLC buffer (proven R4 path)
#pragma unroll
          for (int j = 0; j < 8; j++)
            if (!fastOK || (int)(vw[j] & 0xFFFFu) != k) {
              do {
                vw[j] = __hip_atomic_load(&bs[j], __ATOMIC_RELAXED, __HIP_MEMORY_SCOPE_AGENT);
              } while ((int)(vw[j] & 0xFFFFu) != k);
            }
        }
        u32x4 d0, d1;
#pragma unroll
        for (int j = 0; j < 4; j++) d0[j] = (unsigned int)(vw[j] >> 16);
#pragma unroll
        for (int j = 0; j < 4; j++) d1[j] = (unsigned int)(vw[4 + j] >> 16);
        u32x4* dst = (u32x4*)&A[slot][s][psl * 16];
        dst[0] = d0;
        dst[1] = d1;
      }
      if (k > 0) fastOK = fastOK && (__all((int)good) != 0);
    }
    wg_barrier();   // B1: A[slot] complete

    // ---- P2: gate GEMM (wave = gate) + redundant MLP for out_{k-1} ----
    short8 afr[9];
#pragma unroll
    for (int kt = 0; kt < 9; kt++)
      afr[kt] = *(const short8*)&A[slot][lr][kt * 32 + lg * 8];
    if (k < LSEQ) {
      f32x4 acc = {bv, bv, bv, bv};
#pragma unroll
      for (int kt = 0; kt < 9; kt++)
        acc = __builtin_amdgcn_mfma_f32_16x16x32_bf16(afr[kt], wg_[kt], acc, 0, 0, 0);
#pragma unroll
      for (int r = 0; r < 4; r++) gbuf[w][lg * 4 + r][lr] = acc[r];
    }
    if (k > 0) {
      f32x4 m0 = {b1v0, b1v0, b1v0, b1v0};
      f32x4 m1 = {b1v1, b1v1, b1v1, b1v1};
#pragma unroll
      for (int kt = 0; kt < 8; kt++) {
        m0 = __builtin_amdgcn_mfma_f32_16x16x32_bf16(afr[kt], w1a[kt], m0, 0, 0, 0);
        m1 = __builtin_amdgcn_mfma_f32_16x16x32_bf16(afr[kt], w1b[kt], m1, 0, 0, 0);
      }
      float p[4];
#pragma unroll
      for (int r = 0; r < 4; r++) {
        float v0 = m0[r] > 0.f ? m0[r] : 0.f;
        float v1 = m1[r] > 0.f ? m1[r] : 0.f;
        p[r] = v0 * w2v0 + v1 * w2v1;
        p[r] += __shfl_xor(p[r], 1, 64);
        p[r] += __shfl_xor(p[r], 2, 64);
        p[r] += __shfl_xor(p[r], 4, 64);
        p[r] += __shfl_xor(p[r], 8, 64);
      }
      if (lr == 0) {
#pragma unroll
        for (int r = 0; r < 4; r++) part[w][lg * 4 + r] = p[r];
      }
    }
    wg_barrier();   // B2: gbuf + part ready

    // ---- P3: out reduce + cell update + dual publish (all 256 threads) ----
    {
      float o = 0.f;
      if (k > 0) {
        o = b2v + part[0][cs] + part[1][cs] + part[2][cs] + part[3][cs];
        if (cu == 0 && sl == 0)
          __builtin_nontemporal_store(o, out0 + (size_t)(n0 + cs) * LSEQ + (k - 1));
      }
      if (k < LSEQ) {
        float gi = gbuf[0][cs][cu] + wpv[0] * o;
        float gf = gbuf[1][cs][cu] + wpv[1] * o;
        float gg = gbuf[2][cs][cu] + wpv[2] * o;
        float go = gbuf[3][cs][cu] + wpv[3] * o;
        float c = sigm(gf) * c_reg + sigm(gi) * tanh_(gg);
        c_reg = c;
        float h = sigm(go) * tanh_(c);
        unsigned int hb = f2bf(h);
        unsigned int ho = (unsigned int)__shfl_xor((int)hb, 1, 64);
        if ((cu & 1) == 0) {   // word = [h(cu+1) | h(cu) | tag=k+1]
          unsigned long long wv = (unsigned long long)(unsigned)(k + 1)
                                | ((unsigned long long)hb << 16)
                                | ((unsigned long long)ho << 32);
          const size_t d =
              (((size_t)((k + 1) & 3) * 16 + grp) * 16 + sl) * 128 + cs * 8 + (cu >> 1);
          __asm__ __volatile__("global_store_dwordx2 %0, %1, off sc0"
                               :: "v"(pktF + d), "v"(wv) : "memory");
          __hip_atomic_store(pktS + d, wv, __ATOMIC_RELAXED, __HIP_MEMORY_SCOPE_AGENT);
        }
        A[slot ^ 1][cs][u0 + cu] = (unsigned short)hb;   // own-slice short circuit
        __builtin_nontemporal_store(
            c, out1 + ((size_t)(n0 + cs) * LSEQ + k) * 256 + u0 + cu);
      }
    }
    // no barrier: P3 LDS reads precede own next-B1; gbuf/part rewritten only
    // after B1(k+1)/B2(k+1); A[slot^1] writer regions disjoint.
  }

  __builtin_amdgcn_fence(__ATOMIC_RELEASE, "agent");   // replay safety
}

extern "C" void kernel_launch(void* const* d_in, const int* in_sizes, int n_in,
                              void* d_out, int out_size, void* d_ws, size_t ws_size,
                              hipStream_t stream) {
  const float* x    = (const float*)d_in[0];
  const float* W_ih = (const float*)d_in[1];
  const float* W_hh = (const float*)d_in[2];
  const float* b_ih = (const float*)d_in[3];
  const float* b_hh = (const float*)d_in[4];
  const float* W1   = (const float*)d_in[5];
  const float* b1   = (const float*)d_in[6];
  const float* W2   = (const float*)d_in[7];
  const float* b2   = (const float*)d_in[8];

  unsigned short*     wstream  = (unsigned short*)d_ws;                       // 589,824 B
  unsigned short*     w1stream = (unsigned short*)((char*)d_ws + 589824);     // 65,536 B
  float*              bias     = (float*)((char*)d_ws + 655360);              // 4,096 B
  unsigned int*       xcdid    = (unsigned int*)((char*)d_ws + 659456);       // 1,024 B
  unsigned long long* pktF     = (unsigned long long*)((char*)d_ws + 660480); // 1,048,576 B
  unsigned long long* pktS     = (unsigned long long*)((char*)d_ws + 1709056);// 1,048,576 B

  float* out0 = (float*)d_out;            // [256,2048,1]
  float* out1 = out0 + 256 * LSEQ;        // [256,2048,256]

  prep_kernel<<<1189, 256, 0, stream>>>(W_ih, W_hh, b_ih, b_hh, W1,
                                        wstream, w1stream, bias, pktF, xcdid);
  lstm_main<<<256, 256, 0, stream>>>(x, W_ih, b1, W2, b2, wstream, w1stream, bias,
                                     pktF, pktS, xcdid, out0, out1);
}

// Round 10
// 6968.507 us; speedup vs baseline: 5.7714x; 2.7743x over previous
//
#include <hip/hip_runtime.h>

// LSTM: N=256, L=2048, IN=8, H1=256, H2=128, OUT=1
// 32 WGs = 16 groups x 2 halves. Each WG: 16 samples, 128 hidden units.
// Gate weights (288KB) REGISTER-resident (144 VGPR/lane); W1 in LDS.
// Pair exchange (1024 tagged words/step) via proven primitives only:
//   fast (census-proven same-XCD pair): plain stores + RMW(add 0, sc0) reads
//     -- R7-proven visible, deadlock-free; small volume; s_sleep-throttled.
//   slow (census failed): agent atomics via LLC -- R4-proven (~6ms).
// No trip heuristics, no budgets. 2 barriers/step.
// R10 fix vs R9: W1 LDS copy bound 4096 -> 8192 u64 (was copying HALF of W1;
// waves 4-7 MLP used garbage -> absmax 2e36).

typedef __attribute__((ext_vector_type(8))) short short8;
typedef __attribute__((ext_vector_type(4))) float f32x4;

#define LSEQ 2048

__device__ __forceinline__ unsigned short f2bf(float f) {
  unsigned int u = __float_as_uint(f);
  return (unsigned short)((u + 0x7FFFu + ((u >> 16) & 1u)) >> 16);
}
__device__ __forceinline__ float sigm(float x) {
  float e = __builtin_amdgcn_exp2f(-1.44269504089f * x);
  return __builtin_amdgcn_rcpf(1.0f + e);
}
__device__ __forceinline__ float tanh_(float x) {
  float ax = __builtin_fabsf(x);
  float e = __builtin_amdgcn_exp2f(-2.88539008178f * ax);
  float t = (1.0f - e) * __builtin_amdgcn_rcpf(1.0f + e);
  return __builtin_copysignf(t, x);
}
__device__ __forceinline__ void wg_barrier() {
  __asm__ __volatile__("s_waitcnt lgkmcnt(0)" ::: "memory");
  __builtin_amdgcn_s_barrier();
}
// L2-point atomic read (R7-proven: sees same-XCD plain stores; never L1-stale)
__device__ __forceinline__ unsigned long long l2_read(const unsigned long long* a) {
  unsigned long long old, zero = 0ull;
  __asm__ __volatile__(
      "global_atomic_add_x2 %0, %1, %2, off sc0\n\t"
      "s_waitcnt vmcnt(0)"
      : "=&v"(old) : "v"(a), "v"(zero) : "memory");
  return old;
}
__device__ __forceinline__ void plain_store64(unsigned long long* a, unsigned long long v) {
  __asm__ __volatile__("global_store_dwordx2 %0, %1, off" :: "v"(a), "v"(v) : "memory");
}

// ---------------- prep: frag streams + bias + prev-col + zero pkt/xcdid ----------------
// gate frag f = hf*288 + nt*9 + kt  (hf 0..1, nt 0..31, kt 0..8)
//   lane l,j: col = (nt>>3)*256 + hf*128 + (nt&7)*16 + (l&15)
//             k = kt*32 + (l>>4)*8 + j
//   k<256 -> W_hh[col][k]; 256..263 -> W_ih[col][k-256]; else 0 (prev rank-1)
// w1 frag f = nt*8 + kt (nt 0..7): col = nt*16 + (l&15), k over 256
__global__ void prep_kernel(const float* __restrict__ W_ih, const float* __restrict__ W_hh,
                            const float* __restrict__ b_ih, const float* __restrict__ b_hh,
                            const float* __restrict__ W1,
                            unsigned short* __restrict__ wstream,
                            unsigned short* __restrict__ w1stream,
                            float* __restrict__ bias, float* __restrict__ pw,
                            unsigned int* __restrict__ xcdid,
                            unsigned long long* __restrict__ pkt) {
  int tid = blockIdx.x * 256 + threadIdx.x;
  if (tid < 36864) {                       // 576 gate frags * 64 lanes
    int f = tid >> 6, l = tid & 63;
    int hf = f / 288, rem = f % 288, nt = rem / 9, kt = rem % 9;
    int col = (nt >> 3) * 256 + hf * 128 + (nt & 7) * 16 + (l & 15);
    int k0 = kt * 32 + (l >> 4) * 8;
    unsigned short* dst = wstream + (size_t)f * 512 + l * 8;
#pragma unroll
    for (int j = 0; j < 8; j++) {
      int k = k0 + j;
      float v;
      if (k < 256)      v = W_hh[col * 256 + k];
      else if (k < 264) v = W_ih[col * 9 + (k - 256)];
      else              v = 0.0f;
      dst[j] = f2bf(v);
    }
  } else if (tid < 40960) {                // 64 W1 frags
    int t2 = tid - 36864;
    int f = t2 >> 6, l = t2 & 63;
    int nt = f >> 3, kt = f & 7;
    int col = nt * 16 + (l & 15);
    int k0 = kt * 32 + (l >> 4) * 8;
    unsigned short* dst = w1stream + (size_t)f * 512 + l * 8;
#pragma unroll
    for (int j = 0; j < 8; j++) dst[j] = f2bf(W1[col * 256 + k0 + j]);
  } else if (tid < 41984) {
    int g = tid - 40960;
    bias[g] = b_ih[g] + b_hh[g];
  } else if (tid < 43008) {
    int i = tid - 41984;
    pw[i] = W_ih[i * 9 + 8];               // prev-output column
  } else if (tid < 43040) {
    xcdid[tid - 43008] = 0u;
  } else if (tid < 43040 + 131072) {
    pkt[tid - 43040] = 0ull;               // tag=0 never matches k>=1
  }
}

// ---------------- main: 32 WGs x 512 threads ----------------
__global__ __launch_bounds__(512, 2) void lstm_main(
    const float* __restrict__ x, const float* __restrict__ b1,
    const float* __restrict__ W2, const float* __restrict__ b2,
    const unsigned short* __restrict__ wstream, const unsigned short* __restrict__ w1stream,
    const float* __restrict__ bias, const float* __restrict__ pw,
    unsigned long long* __restrict__ pkt, unsigned int* __restrict__ xcdid,
    float* __restrict__ out0, float* __restrict__ out1) {
  __shared__ unsigned short A[2][16][296];   // [slot][sample][K]: 0..255 h, 256..263 x, rest 0
  __shared__ float gbuf[4][16][128];         // [gate][sample][local unit]
  __shared__ float part[8][17];              // MLP partials [wave][sample]
  __shared__ float pwl[4][128];              // prev-col slice
  __shared__ unsigned short W1l[64 * 512];   // 64 frags x 512 bf16 (64KB)
  __shared__ unsigned int xl[32];
  __shared__ int hdr[4];

  const int tid = threadIdx.x;
  const int w = tid >> 6, l = tid & 63, lr = l & 15, lg = l >> 4;

  // ---- census & pairing (R7-proven) ----
  int my_xcc;
  __asm__ __volatile__("s_getreg_b32 %0, hwreg(HW_REG_XCC_ID)" : "=s"(my_xcc));
  my_xcc &= 7;
  if (tid == 0)
    __hip_atomic_store(&xcdid[blockIdx.x], (unsigned)(my_xcc + 1),
                       __ATOMIC_RELAXED, __HIP_MEMORY_SCOPE_AGENT);
  if (tid < 32) {
    unsigned v;
    do { v = __hip_atomic_load(&xcdid[tid], __ATOMIC_RELAXED, __HIP_MEMORY_SCOPE_AGENT); }
    while (v == 0u);
    xl[tid] = v - 1;
  }
  __syncthreads();
  if (tid == 0) {
    int cnt[8] = {0,0,0,0,0,0,0,0};
    int rank = 0, ok = 1;
    for (int b = 0; b < 32; b++) {
      int xb = (int)xl[b];
      if (xb > 7) { ok = 0; xb = 0; }
      if (b < (int)blockIdx.x && xb == my_xcc) rank++;
      cnt[xb]++;
    }
#pragma unroll
    for (int i = 0; i < 8; i++) ok &= (cnt[i] == 4);
    if (ok) { hdr[0] = 1; hdr[1] = my_xcc * 2 + (rank >> 1); hdr[2] = rank & 1; }
    else    { hdr[0] = 0; hdr[1] = (int)(blockIdx.x >> 1);   hdr[2] = (int)(blockIdx.x & 1); }
  }
  __syncthreads();
  const int fast = hdr[0], gid = hdr[1], hf = hdr[2];
  const int n0 = gid * 16;

  // ---- persistent gate weights in registers (36 frags = 144 VGPRs) ----
  short8 wg_[36];
  {
    const short8* wp = (const short8*)wstream;
#pragma unroll
    for (int ntl = 0; ntl < 4; ntl++)
#pragma unroll
      for (int kt = 0; kt < 9; kt++)
        wg_[ntl * 9 + kt] = wp[(size_t)(hf * 288 + (w * 4 + ntl) * 9 + kt) * 64 + l];
  }
  // W1 -> LDS (64KB = 8192 u64  <-- R10 fix), prev-col slice -> LDS
  {
    const unsigned long long* src = (const unsigned long long*)w1stream;
    unsigned long long* dstl = (unsigned long long*)W1l;
    for (int i = tid; i < 8192; i += 512) dstl[i] = src[i];
    if (tid < 512) pwl[tid >> 7][tid & 127] = pw[(tid >> 7) * 256 + hf * 128 + (tid & 127)];
  }
  float biasv[4];
#pragma unroll
  for (int ntl = 0; ntl < 4; ntl++) {
    int nt = w * 4 + ntl;
    biasv[ntl] = bias[(nt >> 3) * 256 + hf * 128 + (nt & 7) * 16 + lr];
  }
  const float b1v = b1[w * 16 + lr];
  const float w2v = W2[w * 16 + lr];
  const float b2v = b2[0];

  const int cs = tid >> 5, cu4 = (tid & 31) * 4;   // cell: sample, 4 units
  float c0 = 0.f, c1 = 0.f, c2 = 0.f, c3 = 0.f;

  for (int i = tid; i < 2 * 16 * 296; i += 512) ((unsigned short*)A)[i] = 0;

  // x prefetch (threads 496..511: sample tid&15)
  f32x4 xa = {0.f,0.f,0.f,0.f}, xb = {0.f,0.f,0.f,0.f};
  if (tid >= 496) {
    const float* xp = x + (size_t)(n0 + (tid & 15)) * LSEQ * 8;
    xa = *(const f32x4*)xp;
    xb = *(const f32x4*)(xp + 4);
  }
  __syncthreads();

  for (int k = 0; k <= LSEQ; k++) {
    const int slot = k & 1;

    // ---- P1: receive partner's h_{k-1} (2 tagged words/thread) + stage x ----
    if (k > 0) {
      const size_t pb =
          (((size_t)(k & 3) * 16 + gid) * 2 + (hf ^ 1)) * 1024 + 2 * (size_t)tid;
      unsigned long long v0, v1;
      if (fast) {
        unsigned long long z = 0ull;
        __asm__ __volatile__(
            "global_atomic_add_x2 %0, %2, %3, off sc0\n\t"
            "global_atomic_add_x2 %1, %2, %3, off offset:8 sc0\n\t"
            "s_waitcnt vmcnt(0)"
            : "=&v"(v0), "=&v"(v1) : "v"(pkt + pb), "v"(z) : "memory");
        while ((unsigned)(v0 & 0xFFFFu) != (unsigned)k) {
          __builtin_amdgcn_s_sleep(1);
          v0 = l2_read(pkt + pb);
        }
        while ((unsigned)(v1 & 0xFFFFu) != (unsigned)k) {
          __builtin_amdgcn_s_sleep(1);
          v1 = l2_read(pkt + pb + 1);
        }
      } else {
        do { v0 = __hip_atomic_load(pkt + pb, __ATOMIC_RELAXED, __HIP_MEMORY_SCOPE_AGENT); }
        while ((unsigned)(v0 & 0xFFFFu) != (unsigned)k);
        do { v1 = __hip_atomic_load(pkt + pb + 1, __ATOMIC_RELAXED, __HIP_MEMORY_SCOPE_AGENT); }
        while ((unsigned)(v1 & 0xFFFFu) != (unsigned)k);
      }
      const int s = tid >> 5, wu = (2 * tid) & 63;
      unsigned long long pay = ((v0 >> 16) & 0xFFFFFFFFull)
                             | (((v1 >> 16) & 0xFFFFFFFFull) << 32);
      *(unsigned long long*)&A[slot][s][(hf ^ 1) * 128 + wu * 2] = pay;
    }
    if (tid >= 496 && k < LSEQ) {
      const int s = tid & 15;
      unsigned long long w0 = (unsigned long long)f2bf(xa.x)
                            | ((unsigned long long)f2bf(xa.y) << 16)
                            | ((unsigned long long)f2bf(xa.z) << 32)
                            | ((unsigned long long)f2bf(xa.w) << 48);
      unsigned long long w1w = (unsigned long long)f2bf(xb.x)
                             | ((unsigned long long)f2bf(xb.y) << 16)
                             | ((unsigned long long)f2bf(xb.z) << 32)
                             | ((unsigned long long)f2bf(xb.w) << 48);
      *(unsigned long long*)&A[slot][s][256] = w0;
      *(unsigned long long*)&A[slot][s][260] = w1w;
      if (k + 1 < LSEQ) {
        const float* xp = x + ((size_t)(n0 + s) * LSEQ + (k + 1)) * 8;
        xa = *(const f32x4*)xp;
        xb = *(const f32x4*)(xp + 4);
      }
    }
    wg_barrier();   // B1: A[slot] complete (partner h + own h + x)

    // ---- P2: gate GEMM (4 N-tiles/wave, K=288) + redundant MLP for out_{k-1} ----
    if (k < LSEQ) {
      f32x4 acc[4];
#pragma unroll
      for (int ntl = 0; ntl < 4; ntl++)
        acc[ntl] = (f32x4){biasv[ntl], biasv[ntl], biasv[ntl], biasv[ntl]};
#pragma unroll
      for (int kt = 0; kt < 9; kt++) {
        short8 af = *(const short8*)&A[slot][lr][kt * 32 + lg * 8];
#pragma unroll
        for (int ntl = 0; ntl < 4; ntl++)
          acc[ntl] = __builtin_amdgcn_mfma_f32_16x16x32_bf16(af, wg_[ntl * 9 + kt], acc[ntl], 0, 0, 0);
      }
#pragma unroll
      for (int ntl = 0; ntl < 4; ntl++) {
        int nt = w * 4 + ntl;
        int g = nt >> 3, lu = (nt & 7) * 16 + lr;
#pragma unroll
        for (int r = 0; r < 4; r++) gbuf[g][lg * 4 + r][lu] = acc[ntl][r];
      }
    }
    if (k > 0) {
      f32x4 m = {b1v, b1v, b1v, b1v};
#pragma unroll
      for (int kt = 0; kt < 8; kt++) {
        short8 af = *(const short8*)&A[slot][lr][kt * 32 + lg * 8];
        short8 wf = *(const short8*)&W1l[(w * 8 + kt) * 512 + l * 8];
        m = __builtin_amdgcn_mfma_f32_16x16x32_bf16(af, wf, m, 0, 0, 0);
      }
      float p[4];
#pragma unroll
      for (int r = 0; r < 4; r++) {
        float v = m[r] > 0.f ? m[r] : 0.f;
        p[r] = v * w2v;
        p[r] += __shfl_xor(p[r], 1, 64);
        p[r] += __shfl_xor(p[r], 2, 64);
        p[r] += __shfl_xor(p[r], 4, 64);
        p[r] += __shfl_xor(p[r], 8, 64);
      }
      if (lr == 0) {
#pragma unroll
        for (int r = 0; r < 4; r++) part[w][lg * 4 + r] = p[r];
      }
    }
    wg_barrier();   // B2: gbuf + part ready

    // ---- P3: out reduce + cell update (4 cells/thread) + publish ----
    {
      float o = 0.f;
      if (k > 0) {
        o = b2v;
#pragma unroll
        for (int i = 0; i < 8; i++) o += part[i][cs];
        if (hf == 0 && cu4 == 0)
          __builtin_nontemporal_store(o, out0 + (size_t)(n0 + cs) * LSEQ + (k - 1));
      }
      if (k < LSEQ) {
        float h[4];
        f32x4 cv;
#define CELL(J, CREG)                                                        \
        {                                                                    \
          float gi = gbuf[0][cs][cu4 + J] + pwl[0][cu4 + J] * o;             \
          float gf = gbuf[1][cs][cu4 + J] + pwl[1][cu4 + J] * o;             \
          float gg = gbuf[2][cs][cu4 + J] + pwl[2][cu4 + J] * o;             \
          float go = gbuf[3][cs][cu4 + J] + pwl[3][cu4 + J] * o;             \
          float c = sigm(gf) * CREG + sigm(gi) * tanh_(gg);                  \
          CREG = c;                                                          \
          h[J] = sigm(go) * tanh_(c);                                        \
          cv[J] = c;                                                         \
        }
        CELL(0, c0) CELL(1, c1) CELL(2, c2) CELL(3, c3)
#undef CELL
        __builtin_nontemporal_store(cv,
            (f32x4*)(out1 + ((size_t)(n0 + cs) * LSEQ + k) * 256 + hf * 128 + cu4));
        unsigned long long hb0 = f2bf(h[0]), hb1 = f2bf(h[1]);
        unsigned long long hb2 = f2bf(h[2]), hb3 = f2bf(h[3]);
        unsigned long long w0 = (unsigned long long)(unsigned)(k + 1)
                              | (hb0 << 16) | (hb1 << 32);
        unsigned long long w1w = (unsigned long long)(unsigned)(k + 1)
                               | (hb2 << 16) | (hb3 << 32);
        unsigned long long* dst =
            pkt + ((((size_t)((k + 1) & 3) * 16 + gid) * 2 + hf) * 1024 + cs * 64 + (cu4 >> 1));
        if (fast) {
          plain_store64(dst, w0);
          plain_store64(dst + 1, w1w);
        } else {
          __hip_atomic_store(dst,     w0,  __ATOMIC_RELAXED, __HIP_MEMORY_SCOPE_AGENT);
          __hip_atomic_store(dst + 1, w1w, __ATOMIC_RELAXED, __HIP_MEMORY_SCOPE_AGENT);
        }
        // own-half short circuit into next A slot (4 bf16 = one u64)
        *(unsigned long long*)&A[slot ^ 1][cs][hf * 128 + cu4] =
            hb0 | (hb1 << 16) | (hb2 << 32) | (hb3 << 48);
      }
    }
    // no barrier: P3 LDS reads precede own next-B1; gbuf/part rewritten only
    // after B1(k+1)/B2(k+1); A[slot^1] writer regions disjoint.
  }

  __builtin_amdgcn_fence(__ATOMIC_RELEASE, "agent");   // replay safety
}

extern "C" void kernel_launch(void* const* d_in, const int* in_sizes, int n_in,
                              void* d_out, int out_size, void* d_ws, size_t ws_size,
                              hipStream_t stream) {
  const float* x    = (const float*)d_in[0];
  const float* W_ih = (const float*)d_in[1];
  const float* W_hh = (const float*)d_in[2];
  const float* b_ih = (const float*)d_in[3];
  const float* b_hh = (const float*)d_in[4];
  const float* W1   = (const float*)d_in[5];
  const float* b1   = (const float*)d_in[6];
  const float* W2   = (const float*)d_in[7];
  const float* b2   = (const float*)d_in[8];

  unsigned short*     wstream  = (unsigned short*)d_ws;                      // 589,824 B
  unsigned short*     w1stream = (unsigned short*)((char*)d_ws + 589824);    // 65,536 B
  float*              bias     = (float*)((char*)d_ws + 655360);             // 4,096 B
  float*              pw       = (float*)((char*)d_ws + 659456);             // 4,096 B
  unsigned int*       xcdid    = (unsigned int*)((char*)d_ws + 663552);      // 256 B
  unsigned long long* pkt      = (unsigned long long*)((char*)d_ws + 663808);// 1,048,576 B

  float* out0 = (float*)d_out;            // [256,2048,1]
  float* out1 = out0 + 256 * LSEQ;        // [256,2048,256]

  prep_kernel<<<681, 256, 0, stream>>>(W_ih, W_hh, b_ih, b_hh, W1,
                                       wstream, w1stream, bias, pw, xcdid, pkt);
  lstm_main<<<32, 512, 0, stream>>>(x, b1, W2, b2, wstream, w1stream, bias, pw,
                                    pkt, xcdid, out0, out1);
}